// Round 13
// baseline (1985.172 us; speedup 1.0000x reference)
//
#include <hip/hip_runtime.h>

#define VV 32000
#define EE 256
#define HH 512
#define BB 32
#define SS 80
#define TT 80
// decoder rows = B*(T-1) = 2528, padded to 2560 (20 tiles of 128)

typedef __attribute__((ext_vector_type(8))) _Float16 half8;
typedef __attribute__((ext_vector_type(4))) _Float16 half4;
typedef __attribute__((ext_vector_type(4))) float floatx4;
typedef unsigned long long u64;

__device__ __forceinline__ void gload16(const _Float16* g, _Float16* l) {
  __builtin_amdgcn_global_load_lds((const __attribute__((address_space(1))) void*)g,
                                   (__attribute__((address_space(3))) void*)l, 16, 0, 0);
}

__device__ __forceinline__ u64 aload(const u64* p) {
  return __hip_atomic_load(p, __ATOMIC_RELAXED, __HIP_MEMORY_SCOPE_AGENT);
}
__device__ __forceinline__ void astore(u64* p, u64 v) {
  __hip_atomic_store(p, v, __ATOMIC_RELAXED, __HIP_MEMORY_SCOPE_AGENT);
}
__device__ __forceinline__ void astore_f(float* p, float v) {
  __hip_atomic_store(p, v, __ATOMIC_RELAXED, __HIP_MEMORY_SCOPE_AGENT);
}

__device__ __forceinline__ float dot8(half8 a, half8 b, float c) {
  typedef __attribute__((ext_vector_type(2))) _Float16 half2v;
  half2v a0 = {a[0],a[1]}, a1 = {a[2],a[3]}, a2 = {a[4],a[5]}, a3 = {a[6],a[7]};
  half2v b0 = {b[0],b[1]}, b1 = {b[2],b[3]}, b2 = {b[4],b[5]}, b3 = {b[6],b[7]};
  c = __builtin_amdgcn_fdot2(a0, b0, c, false);
  c = __builtin_amdgcn_fdot2(a1, b1, c, false);
  c = __builtin_amdgcn_fdot2(a2, b2, c, false);
  c = __builtin_amdgcn_fdot2(a3, b3, c, false);
  return c;
}

__device__ __forceinline__ float sigm(float x) { return 1.f/(1.f + __expf(-x)); }
__device__ __forceinline__ float tanh_f(float x) { return 2.f/(1.f + __expf(-2.f*x)) - 1.f; }

// ---------------- giE direct GEMM (gather emb fp32 + cvt in staging) --------
__global__ __launch_bounds__(256) void giE_direct(
    const int* __restrict__ src, const float* __restrict__ emb,
    const float* __restrict__ Wih, const float* __restrict__ bih,
    float* __restrict__ gi)
{
  __shared__ _Float16 As[4096];  // 128 x 32
  __shared__ _Float16 Bs[4096];  // 128 x 32
  const int tid = threadIdx.x;
  const int lane = tid & 63;
  const int wv = tid >> 6;
  const int wr = wv >> 1, wc = wv & 1;
  const int mt = blockIdx.y, nt = blockIdx.x;
  floatx4 acc[4][4];
#pragma unroll
  for (int i=0;i<4;++i)
#pragma unroll
    for (int j=0;j<4;++j) acc[i][j] = (floatx4){0.f,0.f,0.f,0.f};
  const int r2 = tid >> 1, cb = (tid & 1) * 16;
  const int tok = src[mt*128 + r2];
  const float* arow = emb + (size_t)tok*EE;
  const float* brow = Wih + (size_t)(nt*128 + r2)*EE;
  const int g8 = (lane >> 4) * 8;
  const int lr = lane & 15;
  for (int kb = 0; kb < EE; kb += 32) {
    __syncthreads();
#pragma unroll
    for (int q = 0; q < 4; ++q) {
      const floatx4 va = *(const floatx4*)(arow + kb + cb + q*4);
      const floatx4 vb = *(const floatx4*)(brow + kb + cb + q*4);
#pragma unroll
      for (int e = 0; e < 4; ++e) {
        As[r2*32 + cb + q*4 + e] = (_Float16)va[e];
        Bs[r2*32 + cb + q*4 + e] = (_Float16)vb[e];
      }
    }
    __syncthreads();
    half8 af[4], bf[4];
#pragma unroll
    for (int i=0;i<4;++i) af[i] = *(const half8*)(As + (wr*64 + i*16 + lr)*32 + g8);
#pragma unroll
    for (int j=0;j<4;++j) bf[j] = *(const half8*)(Bs + (wc*64 + j*16 + lr)*32 + g8);
#pragma unroll
    for (int i=0;i<4;++i)
#pragma unroll
      for (int j=0;j<4;++j)
        acc[i][j] = __builtin_amdgcn_mfma_f32_16x16x32_f16(af[i], bf[j], acc[i][j], 0,0,0);
  }
  const int rm = 4*(lane>>4);
#pragma unroll
  for (int i=0;i<4;++i)
#pragma unroll
    for (int r=0;r<4;++r) {
      const int row = mt*128 + wr*64 + i*16 + rm + r;
#pragma unroll
      for (int j=0;j<4;++j) {
        const int col = nt*128 + wc*64 + j*16 + lr;
        gi[(size_t)row*1536 + col] = acc[i][j][r] + bih[col];
      }
    }
}

// ---------------- logits GEMM, XCD-clustered (r12-proven) --------------------
__global__ __launch_bounds__(256) void logits_gemm(
    const _Float16* __restrict__ A, const _Float16* __restrict__ Bm,
    const float* __restrict__ bias, float* __restrict__ out)
{
  const int p = blockIdx.x;
  const int x = p & 7, s = p >> 3;
  const int nt = x + 8*(s / 20);
  const int mt = s % 20;
  if (nt >= 250) return;
  __shared__ _Float16 As[4096];
  __shared__ _Float16 Bs[4096];
  const int tid = threadIdx.x;
  const int lane = tid & 63;
  const int wv = tid >> 6;
  const int wr = wv >> 1, wc = wv & 1;
  floatx4 acc[4][4];
#pragma unroll
  for (int i=0;i<4;++i)
#pragma unroll
    for (int j=0;j<4;++j) acc[i][j] = (floatx4){0.f,0.f,0.f,0.f};
  const int srow = lane >> 2;
  const int scol = (lane & 3) * 8;
  const _Float16* Ab = A + (size_t)(mt*128)*1024;
  const _Float16* Bb = Bm + (size_t)(nt*128)*1024;
  const int g8 = (lane >> 4) * 8;
  const int lr = lane & 15;
  for (int kb = 0; kb < 1024; kb += 32) {
    __syncthreads();
#pragma unroll
    for (int cc = 0; cc < 2; ++cc) {
      const int c = wv*2 + cc;
      gload16(Ab + (size_t)(c*16 + srow)*1024 + kb + scol, As + c*512);
      gload16(Bb + (size_t)(c*16 + srow)*1024 + kb + scol, Bs + c*512);
    }
    __syncthreads();
    half8 af[4], bf[4];
#pragma unroll
    for (int i=0;i<4;++i) af[i] = *(const half8*)(As + (wr*64 + i*16 + lr)*32 + g8);
#pragma unroll
    for (int j=0;j<4;++j) bf[j] = *(const half8*)(Bs + (wc*64 + j*16 + lr)*32 + g8);
#pragma unroll
    for (int i=0;i<4;++i)
#pragma unroll
      for (int j=0;j<4;++j)
        acc[i][j] = __builtin_amdgcn_mfma_f32_16x16x32_f16(af[i], bf[j], acc[i][j], 0,0,0);
  }
  const int rm = 4*(lane>>4);
#pragma unroll
  for (int i=0;i<4;++i)
#pragma unroll
    for (int r=0;r<4;++r) {
      const int row = mt*128 + wr*64 + i*16 + rm + r;
#pragma unroll
      for (int j=0;j<4;++j) {
        const int col = nt*128 + wc*64 + j*16 + lr;
        if (row < 2528) {
          const int b = row / 79;
          const int t = row - b*79;
          out[(size_t)(b*80 + t + 1)*VV + col] = acc[i][j][r] + bias[col];
        } else {
          out[(size_t)((row - 2528)*80)*VV + col] = 0.f;
        }
      }
    }
}

// ---------------- persistent fused kernel -----------------------------------
// WGs 0..31 producers (r5 core, attention removed; h archived to eo[k][b] /
// harch[t][b], write-once). WGs 32..63 attention workers (race-free via
// archives + flags). WGs 64..255 prep (giD direct GEMM sc1 + cnt, oWh conv).
#define SEQ_SMEM (48*520*2)
__global__ __launch_bounds__(128) void seq_fused(
    const float* __restrict__ eWhh, const float* __restrict__ dWhh,
    const float* __restrict__ ebhh, const float* __restrict__ dbhh,
    const float* __restrict__ giE, float* __restrict__ giD,
    const int* __restrict__ tgt, const float* __restrict__ emb,
    const float* __restrict__ dWih, const float* __restrict__ dbih,
    const float* __restrict__ outW, _Float16* __restrict__ oWh,
    _Float16* __restrict__ h16,
    u64* __restrict__ eo_q,        // [80][32][128] u64  (s, b, word)
    u64* __restrict__ harch_q,     // [79][32][128] u64  (t, b, word)
    _Float16* __restrict__ comb,
    unsigned* __restrict__ flags, unsigned* __restrict__ cnt)
{
  extern __shared__ char smem[];
  const int wg  = blockIdx.x;
  const int tid = threadIdx.x;
  const int lane = tid & 63;
  const int wv = tid >> 6;

  auto waitf = [&](int buf, unsigned tgtv){
    if (tid < 32) {
      while (__hip_atomic_load(&flags[(buf*32 + tid)*32], __ATOMIC_RELAXED,
                               __HIP_MEMORY_SCOPE_AGENT) < tgtv)
        __builtin_amdgcn_s_sleep(2);
    }
    __syncthreads();
  };

  // ======================= attention workers ================================
  if (wg >= 32 && wg < 64) {
    const int B = wg - 32;
    u64* hshw = (u64*)smem;             // [128]
    float* sc = (float*)(hshw + 128);   // [80]
    float* aw = sc + 80;                // [80]
    for (int t = 0; t < TT-1; ++t) {
      const int k = 80 + t;
      const int bw = 1 - (k & 1);
      waitf(bw, (unsigned)(k+2));       // h(t) published -> harch[t] drained
      hshw[tid] = harch_q[((size_t)t*32 + B)*128 + tid];   // write-once: plain
      __syncthreads();
      const half8 hf = *(const half8*)((const _Float16*)hshw + lane*8);
#pragma unroll 4
      for (int i = 0; i < 40; ++i) {
        const int s = wv*40 + i;
        union { u64 q[2]; half8 v; } ev;
        ev.q[0] = eo_q[((size_t)s*32 + B)*128 + lane*2];
        ev.q[1] = eo_q[((size_t)s*32 + B)*128 + lane*2 + 1];
        float pt = dot8(ev.v, hf, 0.f);
#pragma unroll
        for (int o = 32; o; o >>= 1) pt += __shfl_xor(pt, o);
        if (lane == 0) sc[s] = pt;
      }
      __syncthreads();
      if (wv == 0) {
        const float v0 = sc[lane];
        const float v1 = (lane < 16) ? sc[64+lane] : -1e30f;
        float m = fmaxf(v0, v1);
#pragma unroll
        for (int o = 32; o; o >>= 1) m = fmaxf(m, __shfl_xor(m, o));
        const float e0 = __expf(v0 - m);
        const float e1 = (lane < 16) ? __expf(v1 - m) : 0.f;
        float ssum = e0 + e1;
#pragma unroll
        for (int o = 32; o; o >>= 1) ssum += __shfl_xor(ssum, o);
        const float inv = 1.f/ssum;
        aw[lane] = e0*inv;
        if (lane < 16) aw[64+lane] = e1*inv;
      }
      __syncthreads();
      float c0=0.f, c1=0.f, c2=0.f, c3=0.f;
#pragma unroll 8
      for (int s = 0; s < SS; ++s) {
        const float a = aw[s];
        union { u64 q; half4 v; } hv; hv.q = eo_q[((size_t)s*32 + B)*128 + tid];
        c0 += a*(float)hv.v[0]; c1 += a*(float)hv.v[1];
        c2 += a*(float)hv.v[2]; c3 += a*(float)hv.v[3];
      }
      const int cb = (tid >> 2)*16 + (tid & 3)*4;   // true-col base of word tid
      _Float16* cr = comb + ((size_t)B*79 + t)*1024;
      *(u64*)&cr[cb] = hshw[tid];
      union { u64 q; _Float16 h[4]; } cu;
      cu.h[0]=(_Float16)c0; cu.h[1]=(_Float16)c1; cu.h[2]=(_Float16)c2; cu.h[3]=(_Float16)c3;
      *(u64*)&cr[512 + cb] = cu.q;
      __syncthreads();
    }
    return;
  }

  // ======================= prep WGs =========================================
  if (wg >= 64) {
    const int pid = wg - 64;            // 0..191
    _Float16* As = (_Float16*)smem;     // [128][32]
    _Float16* Bs = As + 4096;           // [64][32]
    const int lr = lane & 15;
    const int g8 = (lane >> 4) * 8;
    const int rm = 4*(lane>>4);
    for (int tile = pid; tile < 480; tile += 192) {   // 20 mt x 24 nt (N=64)
      const int mt_ = tile / 24, nt_ = tile % 24;
      floatx4 acc[4][4];
#pragma unroll
      for (int i=0;i<4;++i)
#pragma unroll
        for (int j=0;j<4;++j) acc[i][j] = (floatx4){0.f,0.f,0.f,0.f};
      const int R = mt_*128 + tid;
      int tok = -1;
      if (R < 2528) { const int b_ = R/79, tt = R - b_*79; tok = tgt[b_*80 + tt]; }
      const float* arow = (tok >= 0) ? emb + (size_t)tok*EE : nullptr;
      const int br = tid >> 1, bcb = (tid & 1) * 16;
      const float* brow = dWih + (size_t)(nt_*64 + br)*EE;
      for (int kb = 0; kb < EE; kb += 32) {
        __syncthreads();
        if (arow) {
#pragma unroll
          for (int q = 0; q < 8; ++q) {
            const floatx4 v = *(const floatx4*)(arow + kb + q*4);
#pragma unroll
            for (int e = 0; e < 4; ++e) As[tid*32 + q*4 + e] = (_Float16)v[e];
          }
        } else {
#pragma unroll
          for (int j = 0; j < 32; ++j) As[tid*32 + j] = (_Float16)0.f;
        }
#pragma unroll
        for (int q = 0; q < 4; ++q) {
          const floatx4 v = *(const floatx4*)(brow + kb + bcb + q*4);
#pragma unroll
          for (int e = 0; e < 4; ++e) Bs[br*32 + bcb + q*4 + e] = (_Float16)v[e];
        }
        __syncthreads();
        half8 af[4], bf[4];
#pragma unroll
        for (int i=0;i<4;++i) af[i] = *(const half8*)(As + (wv*64 + i*16 + lr)*32 + g8);
#pragma unroll
        for (int j=0;j<4;++j) bf[j] = *(const half8*)(Bs + (j*16 + lr)*32 + g8);
#pragma unroll
        for (int i=0;i<4;++i)
#pragma unroll
          for (int j=0;j<4;++j)
            acc[i][j] = __builtin_amdgcn_mfma_f32_16x16x32_f16(af[i], bf[j], acc[i][j], 0,0,0);
      }
#pragma unroll
      for (int i=0;i<4;++i)
#pragma unroll
        for (int r=0;r<4;++r) {
          const int row = mt_*128 + wv*64 + i*16 + rm + r;
          if (row < 2528) {
#pragma unroll
            for (int j=0;j<4;++j) {
              const int col = nt_*64 + j*16 + lr;
              astore_f(&giD[(size_t)row*1536 + col], acc[i][j][r] + dbih[col]);
            }
          }
        }
    }
    asm volatile("s_waitcnt vmcnt(0)" ::: "memory");
    __syncthreads();
    if (tid == 0)
      __hip_atomic_fetch_add(cnt, 1u, __ATOMIC_RELAXED, __HIP_MEMORY_SCOPE_AGENT);
    const long total8 = (long)VV*1024/8;
    for (long i = (long)pid*128 + tid; i < total8; i += 192L*128) {
      const float* s_ = outW + i*8;
      const floatx4 a = *(const floatx4*)s_;
      const floatx4 b2 = *(const floatx4*)(s_ + 4);
      half8 h;
      h[0]=(_Float16)a[0]; h[1]=(_Float16)a[1]; h[2]=(_Float16)a[2]; h[3]=(_Float16)a[3];
      h[4]=(_Float16)b2[0]; h[5]=(_Float16)b2[1]; h[6]=(_Float16)b2[2]; h[7]=(_Float16)b2[3];
      *(half8*)(oWh + i*8) = h;
    }
    return;
  }

  // ======================= producers ========================================
  const int w = wg;
  _Float16* whh = (_Float16*)smem;      // [48][520]
  const int lr = lane & 15;
  const int l4 = lane >> 4;
  const int b  = wv*16 + lr;
  const int jc = w*16 + 4*l4;

  auto loadW = [&](const float* W){
    for (int i = tid; i < 48*512; i += 128) {
      const int r = i >> 9, k = i & 511;
      whh[r*520 + k] = (_Float16)W[((size_t)(r>>4)*512 + w*16 + (r&15))*512 + k];
    }
  };
  auto publish = [&](int buf, unsigned val){
    asm volatile("s_waitcnt vmcnt(0)" ::: "memory");
    __syncthreads();
    if (tid == 0)
      __hip_atomic_store(&flags[(buf*32 + w)*32], val, __ATOMIC_RELAXED,
                         __HIP_MEMORY_SCOPE_AGENT);
  };

  const floatx4 ebr = *(const floatx4*)&ebhh[jc];
  const floatx4 ebz = *(const floatx4*)&ebhh[HH + jc];
  const floatx4 ebn = *(const floatx4*)&ebhh[2*HH + jc];
  const floatx4 dbr = *(const floatx4*)&dbhh[jc];
  const floatx4 dbz = *(const floatx4*)&dbhh[HH + jc];
  const floatx4 dbn = *(const floatx4*)&dbhh[2*HH + jc];

  float hp[4] = {0.f, 0.f, 0.f, 0.f};

  auto gru = [&](floatx4 gr, floatx4 gz, floatx4 gn,
                 floatx4 bR, floatx4 bZ, floatx4 bN,
                 const u64* bufR, u64* bufW, u64* arch){
    const u64* hb = bufR + b*128 + l4*2;
    u64 hq[32];
#pragma unroll
    for (int kt = 0; kt < 16; ++kt) {
      hq[2*kt]   = aload(hb + kt*8);
      hq[2*kt+1] = aload(hb + kt*8 + 1);
    }
    floatx4 a0 = (floatx4){0.f,0.f,0.f,0.f}, a1 = a0, a2 = a0;
#pragma unroll
    for (int kt = 0; kt < 16; ++kt) {
      union { u64 q[2]; half8 v; } hu;
      hu.q[0] = hq[2*kt]; hu.q[1] = hq[2*kt+1];
      const int ko = kt*32 + l4*8;
      const half8 x0 = *(const half8*)&whh[(     lr)*520 + ko];
      const half8 x1 = *(const half8*)&whh[(16 + lr)*520 + ko];
      const half8 x2 = *(const half8*)&whh[(32 + lr)*520 + ko];
      a0 = __builtin_amdgcn_mfma_f32_16x16x32_f16(x0, hu.v, a0, 0,0,0);
      a1 = __builtin_amdgcn_mfma_f32_16x16x32_f16(x1, hu.v, a1, 0,0,0);
      a2 = __builtin_amdgcn_mfma_f32_16x16x32_f16(x2, hu.v, a2, 0,0,0);
    }
    union { u64 q; _Float16 h[4]; } hw;
#pragma unroll
    for (int r = 0; r < 4; ++r) {
      const float rg = sigm(gr[r] + a0[r] + bR[r]);
      const float zg = sigm(gz[r] + a1[r] + bZ[r]);
      const float ng = tanh_f(gn[r] + rg*(a2[r] + bN[r]));
      const float hn = (1.f - zg)*ng + zg*hp[r];
      hp[r] = hn;
      hw.h[r] = (_Float16)hn;
    }
    astore(bufW + b*128 + w*4 + l4, hw.q);
    astore(arch + b*128 + w*4 + l4, hw.q);
  };

  astore((u64*)h16 + w*128 + tid, 0ull);
  loadW(eWhh);
  publish(0, 1);

  for (int k = 0; k < SS; ++k) {                 // encoder
    const int p = k & 1;
    const float* girow = giE + (size_t)(b*SS + k)*1536 + jc;
    const floatx4 gr = *(const floatx4*)(girow);
    const floatx4 gz = *(const floatx4*)(girow + HH);
    const floatx4 gn = *(const floatx4*)(girow + 2*HH);
    waitf(p, (unsigned)(k+1));
    gru(gr, gz, gn, ebr, ebz, ebn,
        (u64*)h16 + (size_t)p*(BB*HH/4), (u64*)h16 + (size_t)(1-p)*(BB*HH/4),
        eo_q + (size_t)k*32*128);
    publish(1-p, (unsigned)(k+2));
  }

  if (tid == 0) {                                // gate: giD ready
    while (__hip_atomic_load(cnt, __ATOMIC_RELAXED, __HIP_MEMORY_SCOPE_AGENT) < 192u)
      __builtin_amdgcn_s_sleep(8);
  }
  __syncthreads();
  loadW(dWhh);
  __syncthreads();

  for (int t = 0; t < TT-1; ++t) {               // decoder
    const int k = 80 + t;
    const int p = k & 1;
    const float* girow = giD + (size_t)(b*79 + t)*1536 + jc;
    const floatx4 gr = *(const floatx4*)(girow);
    const floatx4 gz = *(const floatx4*)(girow + HH);
    const floatx4 gn = *(const floatx4*)(girow + 2*HH);
    waitf(p, (unsigned)(k+1));
    gru(gr, gz, gn, dbr, dbz, dbn,
        (u64*)h16 + (size_t)p*(BB*HH/4), (u64*)h16 + (size_t)(1-p)*(BB*HH/4),
        harch_q + (size_t)t*32*128);
    publish(1-p, (unsigned)(k+2));
  }
}

extern "C" void kernel_launch(void* const* d_in, const int* in_sizes, int n_in,
                              void* d_out, int out_size, void* d_ws, size_t ws_size,
                              hipStream_t stream) {
  (void)in_sizes; (void)n_in; (void)out_size; (void)ws_size;
  const int*   src  = (const int*)d_in[0];
  const int*   tgt  = (const int*)d_in[1];
  const float* emb  = (const float*)d_in[2];
  const float* eWih = (const float*)d_in[3];
  const float* eWhh = (const float*)d_in[4];
  const float* ebih = (const float*)d_in[5];
  const float* ebhh = (const float*)d_in[6];
  const float* dWih = (const float*)d_in[7];
  const float* dWhh = (const float*)d_in[8];
  const float* dbih = (const float*)d_in[9];
  const float* dbhh = (const float*)d_in[10];
  const float* outW = (const float*)d_in[11];
  const float* outb = (const float*)d_in[12];
  float* out = (float*)d_out;

  char* p = (char*)d_ws;
  auto alloc = [&](size_t n){ char* r = p; p += (n + 255) & ~(size_t)255; return r; };
  _Float16* oWh  = (_Float16*)alloc((size_t)VV*1024*2);
  float*    giE  = (float*)alloc((size_t)2560*1536*4);
  float*    giD  = (float*)alloc((size_t)2560*1536*4);
  _Float16* h16  = (_Float16*)alloc((size_t)2*BB*HH*2);
  u64*      eo_q = (u64*)alloc((size_t)SS*32*128*8);
  u64*      harch= (u64*)alloc((size_t)79*32*128*8);
  _Float16* comb = (_Float16*)alloc((size_t)2560*1024*2);
  unsigned* flags= (unsigned*)alloc(2*32*128 + 256);
  unsigned* cnt  = flags + 2*32*32;

  hipMemsetAsync(flags, 0, 2*32*128 + 256, stream);
  giE_direct<<<dim3(12,20), 256, 0, stream>>>(src, emb, eWih, ebih, giE);
  hipFuncSetAttribute((const void*)seq_fused,
                      hipFuncAttributeMaxDynamicSharedMemorySize, SEQ_SMEM);
  seq_fused<<<256, 128, SEQ_SMEM, stream>>>(
      eWhh, dWhh, ebhh, dbhh, giE, giD, tgt, emb, dWih, dbih, outW, oWh,
      h16, eo_q, harch, comb, flags, cnt);
  logits_gemm<<<5120, 256, 0, stream>>>(comb, oWh, outb, out);
}

// Round 14
// 1896.872 us; speedup vs baseline: 1.0466x; 1.0466x over previous
//
#include <hip/hip_runtime.h>

#define VV 32000
#define EE 256
#define HH 512
#define BB 32
#define SS 80
#define TT 80
// decoder rows = B*(T-1) = 2528, padded to 2560 (20 tiles of 128)

typedef __attribute__((ext_vector_type(8))) _Float16 half8;
typedef __attribute__((ext_vector_type(4))) _Float16 half4;
typedef __attribute__((ext_vector_type(4))) float floatx4;
typedef unsigned long long u64;

__device__ __forceinline__ void gload16(const _Float16* g, _Float16* l) {
  __builtin_amdgcn_global_load_lds((const __attribute__((address_space(1))) void*)g,
                                   (__attribute__((address_space(3))) void*)l, 16, 0, 0);
}

__device__ __forceinline__ u64 aload(const u64* p) {
  return __hip_atomic_load(p, __ATOMIC_RELAXED, __HIP_MEMORY_SCOPE_AGENT);
}
__device__ __forceinline__ void astore(u64* p, u64 v) {
  __hip_atomic_store(p, v, __ATOMIC_RELAXED, __HIP_MEMORY_SCOPE_AGENT);
}

__device__ __forceinline__ float dot8(half8 a, half8 b, float c) {
  typedef __attribute__((ext_vector_type(2))) _Float16 half2v;
  half2v a0 = {a[0],a[1]}, a1 = {a[2],a[3]}, a2 = {a[4],a[5]}, a3 = {a[6],a[7]};
  half2v b0 = {b[0],b[1]}, b1 = {b[2],b[3]}, b2 = {b[4],b[5]}, b3 = {b[6],b[7]};
  c = __builtin_amdgcn_fdot2(a0, b0, c, false);
  c = __builtin_amdgcn_fdot2(a1, b1, c, false);
  c = __builtin_amdgcn_fdot2(a2, b2, c, false);
  c = __builtin_amdgcn_fdot2(a3, b3, c, false);
  return c;
}

__device__ __forceinline__ float sigm(float x) { return 1.f/(1.f + __expf(-x)); }
__device__ __forceinline__ float tanh_f(float x) { return 2.f/(1.f + __expf(-2.f*x)) - 1.f; }

// ---------------- giE direct GEMM (gather emb fp32 + cvt in staging) --------
// r13-proven. gi[R*1536+col] = emb[src[R]] . Wih[col] + bih[col].
__global__ __launch_bounds__(256) void giE_direct(
    const int* __restrict__ src, const float* __restrict__ emb,
    const float* __restrict__ Wih, const float* __restrict__ bih,
    float* __restrict__ gi)
{
  __shared__ _Float16 As[4096];  // 128 x 32
  __shared__ _Float16 Bs[4096];  // 128 x 32
  const int tid = threadIdx.x;
  const int lane = tid & 63;
  const int wv = tid >> 6;
  const int wr = wv >> 1, wc = wv & 1;
  const int mt = blockIdx.y, nt = blockIdx.x;
  floatx4 acc[4][4];
#pragma unroll
  for (int i=0;i<4;++i)
#pragma unroll
    for (int j=0;j<4;++j) acc[i][j] = (floatx4){0.f,0.f,0.f,0.f};
  const int r2 = tid >> 1, cb = (tid & 1) * 16;
  const int tok = src[mt*128 + r2];
  const float* arow = emb + (size_t)tok*EE;
  const float* brow = Wih + (size_t)(nt*128 + r2)*EE;
  const int g8 = (lane >> 4) * 8;
  const int lr = lane & 15;
  for (int kb = 0; kb < EE; kb += 32) {
    __syncthreads();
#pragma unroll
    for (int q = 0; q < 4; ++q) {
      const floatx4 va = *(const floatx4*)(arow + kb + cb + q*4);
      const floatx4 vb = *(const floatx4*)(brow + kb + cb + q*4);
#pragma unroll
      for (int e = 0; e < 4; ++e) {
        As[r2*32 + cb + q*4 + e] = (_Float16)va[e];
        Bs[r2*32 + cb + q*4 + e] = (_Float16)vb[e];
      }
    }
    __syncthreads();
    half8 af[4], bf[4];
#pragma unroll
    for (int i=0;i<4;++i) af[i] = *(const half8*)(As + (wr*64 + i*16 + lr)*32 + g8);
#pragma unroll
    for (int j=0;j<4;++j) bf[j] = *(const half8*)(Bs + (wc*64 + j*16 + lr)*32 + g8);
#pragma unroll
    for (int i=0;i<4;++i)
#pragma unroll
      for (int j=0;j<4;++j)
        acc[i][j] = __builtin_amdgcn_mfma_f32_16x16x32_f16(af[i], bf[j], acc[i][j], 0,0,0);
  }
  const int rm = 4*(lane>>4);
#pragma unroll
  for (int i=0;i<4;++i)
#pragma unroll
    for (int r=0;r<4;++r) {
      const int row = mt*128 + wr*64 + i*16 + rm + r;
#pragma unroll
      for (int j=0;j<4;++j) {
        const int col = nt*128 + wc*64 + j*16 + lr;
        gi[(size_t)row*1536 + col] = acc[i][j][r] + bih[col];
      }
    }
}

// ---------------- giD direct GEMM (tgt-mapped rows) -------------------------
// row R -> b=R/79, t=R%79, token tgt[b*80+t]; rows >= 2528 are pad (A=0,
// stores skipped). gi[R*1536+col] = emb[tok] . dWih[col] + dbih[col].
__global__ __launch_bounds__(256) void giD_direct(
    const int* __restrict__ tgt, const float* __restrict__ emb,
    const float* __restrict__ Wih, const float* __restrict__ bih,
    float* __restrict__ gi)
{
  __shared__ _Float16 As[4096];  // 128 x 32
  __shared__ _Float16 Bs[4096];  // 128 x 32
  const int tid = threadIdx.x;
  const int lane = tid & 63;
  const int wv = tid >> 6;
  const int wr = wv >> 1, wc = wv & 1;
  const int mt = blockIdx.y, nt = blockIdx.x;
  floatx4 acc[4][4];
#pragma unroll
  for (int i=0;i<4;++i)
#pragma unroll
    for (int j=0;j<4;++j) acc[i][j] = (floatx4){0.f,0.f,0.f,0.f};
  const int r2 = tid >> 1, cb = (tid & 1) * 16;
  const int R = mt*128 + r2;
  int tok = -1;
  if (R < 2528) { const int b_ = R/79, tt = R - b_*79; tok = tgt[b_*80 + tt]; }
  const float* arow = (tok >= 0) ? emb + (size_t)tok*EE : nullptr;
  const float* brow = Wih + (size_t)(nt*128 + r2)*EE;
  const int g8 = (lane >> 4) * 8;
  const int lr = lane & 15;
  for (int kb = 0; kb < EE; kb += 32) {
    __syncthreads();
    if (arow) {
#pragma unroll
      for (int q = 0; q < 4; ++q) {
        const floatx4 va = *(const floatx4*)(arow + kb + cb + q*4);
#pragma unroll
        for (int e = 0; e < 4; ++e) As[r2*32 + cb + q*4 + e] = (_Float16)va[e];
      }
    } else {
#pragma unroll
      for (int q = 0; q < 16; ++q) As[r2*32 + cb + q] = (_Float16)0.f;
    }
#pragma unroll
    for (int q = 0; q < 4; ++q) {
      const floatx4 vb = *(const floatx4*)(brow + kb + cb + q*4);
#pragma unroll
      for (int e = 0; e < 4; ++e) Bs[r2*32 + cb + q*4 + e] = (_Float16)vb[e];
    }
    __syncthreads();
    half8 af[4], bf[4];
#pragma unroll
    for (int i=0;i<4;++i) af[i] = *(const half8*)(As + (wr*64 + i*16 + lr)*32 + g8);
#pragma unroll
    for (int j=0;j<4;++j) bf[j] = *(const half8*)(Bs + (wc*64 + j*16 + lr)*32 + g8);
#pragma unroll
    for (int i=0;i<4;++i)
#pragma unroll
      for (int j=0;j<4;++j)
        acc[i][j] = __builtin_amdgcn_mfma_f32_16x16x32_f16(af[i], bf[j], acc[i][j], 0,0,0);
  }
  const int rm = 4*(lane>>4);
#pragma unroll
  for (int i=0;i<4;++i)
#pragma unroll
    for (int r=0;r<4;++r) {
      const int row = mt*128 + wr*64 + i*16 + rm + r;
      if (row < 2528) {
#pragma unroll
        for (int j=0;j<4;++j) {
          const int col = nt*128 + wc*64 + j*16 + lr;
          gi[(size_t)row*1536 + col] = acc[i][j][r] + bih[col];
        }
      }
    }
}

// ---------------- outW fp32 -> fp16 (vectorized) -----------------------------
__global__ __launch_bounds__(256) void oWh_conv(
    const float* __restrict__ ow, _Float16* __restrict__ owh)
{
  const long total8 = (long)VV*1024/8;
  for (long i = (long)blockIdx.x*256 + threadIdx.x; i < total8; i += (long)gridDim.x*256) {
    const float* s_ = ow + i*8;
    const floatx4 a = *(const floatx4*)s_;
    const floatx4 b = *(const floatx4*)(s_ + 4);
    half8 h;
    h[0]=(_Float16)a[0]; h[1]=(_Float16)a[1]; h[2]=(_Float16)a[2]; h[3]=(_Float16)a[3];
    h[4]=(_Float16)b[0]; h[5]=(_Float16)b[1]; h[6]=(_Float16)b[2]; h[7]=(_Float16)b[3];
    *(half8*)(owh + i*8) = h;
  }
}

// ---------------- logits GEMM, XCD-clustered (r12-proven) --------------------
__global__ __launch_bounds__(256) void logits_gemm(
    const _Float16* __restrict__ A, const _Float16* __restrict__ Bm,
    const float* __restrict__ bias, float* __restrict__ out)
{
  const int p = blockIdx.x;
  const int x = p & 7, s = p >> 3;
  const int nt = x + 8*(s / 20);
  const int mt = s % 20;
  if (nt >= 250) return;
  __shared__ _Float16 As[4096];
  __shared__ _Float16 Bs[4096];
  const int tid = threadIdx.x;
  const int lane = tid & 63;
  const int wv = tid >> 6;
  const int wr = wv >> 1, wc = wv & 1;
  floatx4 acc[4][4];
#pragma unroll
  for (int i=0;i<4;++i)
#pragma unroll
    for (int j=0;j<4;++j) acc[i][j] = (floatx4){0.f,0.f,0.f,0.f};
  const int srow = lane >> 2;
  const int scol = (lane & 3) * 8;
  const _Float16* Ab = A + (size_t)(mt*128)*1024;
  const _Float16* Bb = Bm + (size_t)(nt*128)*1024;
  const int g8 = (lane >> 4) * 8;
  const int lr = lane & 15;
  for (int kb = 0; kb < 1024; kb += 32) {
    __syncthreads();
#pragma unroll
    for (int cc = 0; cc < 2; ++cc) {
      const int c = wv*2 + cc;
      gload16(Ab + (size_t)(c*16 + srow)*1024 + kb + scol, As + c*512);
      gload16(Bb + (size_t)(c*16 + srow)*1024 + kb + scol, Bs + c*512);
    }
    __syncthreads();
    half8 af[4], bf[4];
#pragma unroll
    for (int i=0;i<4;++i) af[i] = *(const half8*)(As + (wr*64 + i*16 + lr)*32 + g8);
#pragma unroll
    for (int j=0;j<4;++j) bf[j] = *(const half8*)(Bs + (wc*64 + j*16 + lr)*32 + g8);
#pragma unroll
    for (int i=0;i<4;++i)
#pragma unroll
      for (int j=0;j<4;++j)
        acc[i][j] = __builtin_amdgcn_mfma_f32_16x16x32_f16(af[i], bf[j], acc[i][j], 0,0,0);
  }
  const int rm = 4*(lane>>4);
#pragma unroll
  for (int i=0;i<4;++i)
#pragma unroll
    for (int r=0;r<4;++r) {
      const int row = mt*128 + wr*64 + i*16 + rm + r;
#pragma unroll
      for (int j=0;j<4;++j) {
        const int col = nt*128 + wc*64 + j*16 + lr;
        if (row < 2528) {
          const int b = row / 79;
          const int t = row - b*79;
          out[(size_t)(b*80 + t + 1)*VV + col] = acc[i][j][r] + bias[col];
        } else {
          out[(size_t)((row - 2528)*80)*VV + col] = 0.f;
        }
      }
    }
}

// ---------------- fused recurrence (EXACT r12; proven 1521us) ----------------
// 32 WGs x 128 threads. WG w owns h cols [w*16,w*16+16); Whh slice in LDS.
// Producer: sc1 data stores -> vmcnt(0) -> monotone step number to its OWN
// flag line. Consumer: 32 lanes poll the 32 producer flags, then burst-load h.
// Ping-pong depth 2. Decoder attention sits between publish(k) and wait(k+1),
// i.e. fully hidden inside the sync window (r13 lesson).
#define SEQ_SMEM ((48*520 + 80*512 + 512)*2 + 160*4)
__global__ __launch_bounds__(128) void seq_fused(
    const float* __restrict__ eWhh, const float* __restrict__ dWhh,
    const float* __restrict__ ebhh, const float* __restrict__ dbhh,
    const float* __restrict__ giE, const float* __restrict__ giD,
    _Float16* __restrict__ h16,    // ping-pong 2 x 32 x 512 fp16
    _Float16* __restrict__ comb,
    unsigned* __restrict__ flags)  // [2][32] monotone counters, 128B apart
{
  extern __shared__ char smem[];
  _Float16* whh  = (_Float16*)smem;        // [48][520] fp16 (padded rows)
  _Float16* eo_l = whh + 48*520;           // [80][512] fp16
  _Float16* hsh  = eo_l + 80*512;          // [512]
  float* sc = (float*)(hsh + 512);         // [80]
  float* aw = sc + 80;                     // [80]

  const int w = blockIdx.x;
  const int tid = threadIdx.x;
  const int lane = tid & 63;
  const int wv = tid >> 6;            // 0..1 batch group
  const int lr = lane & 15;
  const int l4 = lane >> 4;           // 0..3
  const int b  = wv*16 + lr;          // batch this thread covers
  const int jc = w*16 + 4*l4;         // global h-col base (4 wide)

  auto loadW = [&](const float* W){
    for (int i = tid; i < 48*512; i += 128) {
      const int r = i >> 9, k = i & 511;
      whh[r*520 + k] = (_Float16)W[((size_t)(r>>4)*512 + w*16 + (r&15))*512 + k];
    }
  };
  auto wait_flags = [&](int buf, unsigned tgt){
    if (tid < 32) {
      while (__hip_atomic_load(&flags[(buf*32 + tid)*32], __ATOMIC_RELAXED,
                               __HIP_MEMORY_SCOPE_AGENT) < tgt)
        __builtin_amdgcn_s_sleep(1);
    }
    __syncthreads();
  };
  auto publish = [&](int buf, unsigned val){
    asm volatile("s_waitcnt vmcnt(0)" ::: "memory");   // all sc1 data stores done
    __syncthreads();
    if (tid == 0)
      __hip_atomic_store(&flags[(buf*32 + w)*32], val, __ATOMIC_RELAXED,
                         __HIP_MEMORY_SCOPE_AGENT);
  };

  const floatx4 ebr = *(const floatx4*)&ebhh[jc];
  const floatx4 ebz = *(const floatx4*)&ebhh[HH + jc];
  const floatx4 ebn = *(const floatx4*)&ebhh[2*HH + jc];
  const floatx4 dbr = *(const floatx4*)&dbhh[jc];
  const floatx4 dbz = *(const floatx4*)&dbhh[HH + jc];
  const floatx4 dbn = *(const floatx4*)&dbhh[2*HH + jc];

  float hp[4] = {0.f, 0.f, 0.f, 0.f};   // fp32 h_prev (batch b, cols jc..jc+3)

  auto gru = [&](floatx4 gr, floatx4 gz, floatx4 gn,
                 floatx4 bR, floatx4 bZ, floatx4 bN,
                 const u64* bufR, u64* bufW, _Float16* stash){
    const u64* hb = bufR + b*128 + l4*2;
    u64 hq[32];
#pragma unroll
    for (int kt = 0; kt < 16; ++kt) {
      hq[2*kt]   = aload(hb + kt*8);
      hq[2*kt+1] = aload(hb + kt*8 + 1);
    }
    u64 sq = 0;
    if (stash) sq = aload(bufR + w*128 + tid);
    floatx4 a0 = (floatx4){0.f,0.f,0.f,0.f}, a1 = a0, a2 = a0;
#pragma unroll
    for (int kt = 0; kt < 16; ++kt) {
      union { u64 q[2]; half8 v; } hu;
      hu.q[0] = hq[2*kt]; hu.q[1] = hq[2*kt+1];
      const int ko = kt*32 + l4*8;
      const half8 x0 = *(const half8*)&whh[(     lr)*520 + ko];
      const half8 x1 = *(const half8*)&whh[(16 + lr)*520 + ko];
      const half8 x2 = *(const half8*)&whh[(32 + lr)*520 + ko];
      a0 = __builtin_amdgcn_mfma_f32_16x16x32_f16(x0, hu.v, a0, 0,0,0);
      a1 = __builtin_amdgcn_mfma_f32_16x16x32_f16(x1, hu.v, a1, 0,0,0);
      a2 = __builtin_amdgcn_mfma_f32_16x16x32_f16(x2, hu.v, a2, 0,0,0);
    }
    union { u64 q; _Float16 h[4]; } hw;
#pragma unroll
    for (int r = 0; r < 4; ++r) {
      const float rg = sigm(gr[r] + a0[r] + bR[r]);
      const float zg = sigm(gz[r] + a1[r] + bZ[r]);
      const float ng = tanh_f(gn[r] + rg*(a2[r] + bN[r]));
      const float hn = (1.f - zg)*ng + zg*hp[r];
      hp[r] = hn;
      hw.h[r] = (_Float16)hn;
    }
    astore(bufW + b*128 + w*4 + l4, hw.q);
    if (stash) *(u64*)&stash[tid*4] = sq;
  };

  auto attention = [&](int trow){
    const half8 hf = *(const half8*)&hsh[lane*8];
#pragma unroll 4
    for (int i = 0; i < 40; ++i) {
      const int s = wv*40 + i;
      const half8 ev = *(const half8*)&eo_l[s*512 + lane*8];
      float pt = dot8(ev, hf, 0.f);
#pragma unroll
      for (int o = 32; o; o >>= 1) pt += __shfl_xor(pt, o);
      if (lane == 0) sc[s] = pt;
    }
    __syncthreads();
    if (wv == 0) {
      const float v0 = sc[lane];
      const float v1 = (lane < 16) ? sc[64+lane] : -1e30f;
      float m = fmaxf(v0, v1);
#pragma unroll
      for (int o = 32; o; o >>= 1) m = fmaxf(m, __shfl_xor(m, o));
      const float e0 = __expf(v0 - m);
      const float e1 = (lane < 16) ? __expf(v1 - m) : 0.f;
      float ssum = e0 + e1;
#pragma unroll
      for (int o = 32; o; o >>= 1) ssum += __shfl_xor(ssum, o);
      const float inv = 1.f/ssum;
      aw[lane] = e0*inv;
      if (lane < 16) aw[64+lane] = e1*inv;
    }
    __syncthreads();
    float c0=0.f, c1=0.f, c2=0.f, c3=0.f;
#pragma unroll 8
    for (int s = 0; s < SS; ++s) {
      const float a = aw[s];
      const half4 hv = *(const half4*)&eo_l[s*512 + tid*4];
      c0 += a*(float)hv[0]; c1 += a*(float)hv[1];
      c2 += a*(float)hv[2]; c3 += a*(float)hv[3];
    }
    _Float16* cr = comb + ((size_t)w*79 + trow)*1024;
    *(u64*)&cr[tid*4] = *(const u64*)&hsh[tid*4];
    union { u64 q; _Float16 h[4]; } cu;
    cu.h[0]=(_Float16)c0; cu.h[1]=(_Float16)c1; cu.h[2]=(_Float16)c2; cu.h[3]=(_Float16)c3;
    *(u64*)&cr[512 + tid*4] = cu.q;
  };

  // init ping buffer 0 (own word), load enc weights, publish step 0
  astore((u64*)h16 + w*128 + tid, 0ull);
  loadW(eWhh);
  publish(0, 1);

  // -------- encoder: k = 0..79 --------
  for (int k = 0; k < SS; ++k) {
    const int p = k & 1;
    const float* girow = giE + (size_t)(b*SS + k)*1536 + jc;
    const floatx4 gr = *(const floatx4*)(girow);          // prefetch pre-wait
    const floatx4 gz = *(const floatx4*)(girow + HH);
    const floatx4 gn = *(const floatx4*)(girow + 2*HH);
    wait_flags(p, (unsigned)(k+1));
    gru(gr, gz, gn, ebr, ebz, ebn,
        (u64*)h16 + (size_t)p*(BB*HH/4), (u64*)h16 + (size_t)(1-p)*(BB*HH/4),
        (k > 0) ? (eo_l + (k-1)*512) : nullptr);
    publish(1-p, (unsigned)(k+2));
  }

  // -------- decoder: k = 80..158 (t = k-80) --------
  __syncthreads();
  loadW(dWhh);
  __syncthreads();
  for (int t = 0; t < TT-1; ++t) {
    const int k = 80 + t;
    const int p = k & 1;
    const float* girow = giD + (size_t)(b*79 + t)*1536 + jc;
    const floatx4 gr = *(const floatx4*)(girow);
    const floatx4 gz = *(const floatx4*)(girow + HH);
    const floatx4 gn = *(const floatx4*)(girow + 2*HH);
    wait_flags(p, (unsigned)(k+1));
    gru(gr, gz, gn, dbr, dbz, dbn,
        (u64*)h16 + (size_t)p*(BB*HH/4), (u64*)h16 + (size_t)(1-p)*(BB*HH/4),
        (t == 0) ? (eo_l + 79*512) : hsh);   // t=0: enc h(79); else h(t-1)
    publish(1-p, (unsigned)(k+2));
    if (t > 0) { __syncthreads(); attention(t-1); }   // hidden in sync window
  }
  // final: attention(78) on h(158) (buffer 1, flag val 160)
  wait_flags(1, 160u);
  {
    const u64 q = aload((const u64*)h16 + (size_t)1*(BB*HH/4) + w*128 + tid);
    *(u64*)&hsh[tid*4] = q;
  }
  __syncthreads();
  attention(TT-2);
}

extern "C" void kernel_launch(void* const* d_in, const int* in_sizes, int n_in,
                              void* d_out, int out_size, void* d_ws, size_t ws_size,
                              hipStream_t stream) {
  (void)in_sizes; (void)n_in; (void)out_size; (void)ws_size;
  const int*   src  = (const int*)d_in[0];
  const int*   tgt  = (const int*)d_in[1];
  const float* emb  = (const float*)d_in[2];
  const float* eWih = (const float*)d_in[3];
  const float* eWhh = (const float*)d_in[4];
  const float* ebih = (const float*)d_in[5];
  const float* ebhh = (const float*)d_in[6];
  const float* dWih = (const float*)d_in[7];
  const float* dWhh = (const float*)d_in[8];
  const float* dbih = (const float*)d_in[9];
  const float* dbhh = (const float*)d_in[10];
  const float* outW = (const float*)d_in[11];
  const float* outb = (const float*)d_in[12];
  float* out = (float*)d_out;

  char* p = (char*)d_ws;
  auto alloc = [&](size_t n){ char* r = p; p += (n + 255) & ~(size_t)255; return r; };
  _Float16* oWh  = (_Float16*)alloc((size_t)VV*1024*2);
  float*    giE  = (float*)alloc((size_t)2560*1536*4);
  float*    giD  = (float*)alloc((size_t)2560*1536*4);
  _Float16* h16  = (_Float16*)alloc((size_t)2*BB*HH*2);   // ping-pong
  _Float16* comb = (_Float16*)alloc((size_t)2560*1024*2);
  unsigned* flags= (unsigned*)alloc(2*32*128);

  hipMemsetAsync(flags, 0, 2*32*128, stream);
  giE_direct<<<dim3(12,20), 256, 0, stream>>>(src, emb, eWih, ebih, giE);
  giD_direct<<<dim3(12,20), 256, 0, stream>>>(tgt, emb, dWih, dbih, giD);
  oWh_conv<<<1024, 256, 0, stream>>>(outW, oWh);
  hipFuncSetAttribute((const void*)seq_fused,
                      hipFuncAttributeMaxDynamicSharedMemorySize, SEQ_SMEM);
  seq_fused<<<32, 128, SEQ_SMEM, stream>>>(eWhh, dWhh, ebhh, dbhh, giE, giD,
                                           h16, comb, flags);
  logits_gemm<<<5120, 256, 0, stream>>>(comb, oWh, outb, out);
}

// Round 15
// 986.740 us; speedup vs baseline: 2.0118x; 1.9224x over previous
//
#include <hip/hip_runtime.h>

#define VV 32000
#define EE 256
#define HH 512
#define BB 32
#define SS 80
#define TT 80
// decoder rows = B*(T-1) = 2528, padded to 2560 (20 tiles of 128)

typedef __attribute__((ext_vector_type(8))) _Float16 half8;
typedef __attribute__((ext_vector_type(4))) _Float16 half4;
typedef __attribute__((ext_vector_type(4))) float floatx4;
typedef unsigned long long u64;

__device__ __forceinline__ void gload16(const _Float16* g, _Float16* l) {
  __builtin_amdgcn_global_load_lds((const __attribute__((address_space(1))) void*)g,
                                   (__attribute__((address_space(3))) void*)l, 16, 0, 0);
}

__device__ __forceinline__ u64 aload(const u64* p) {
  return __hip_atomic_load(p, __ATOMIC_RELAXED, __HIP_MEMORY_SCOPE_AGENT);
}
__device__ __forceinline__ void astore(u64* p, u64 v) {
  __hip_atomic_store(p, v, __ATOMIC_RELAXED, __HIP_MEMORY_SCOPE_AGENT);
}

// ---- 15-bit packing (r9-proven): |h|<=1 so fp16 bit14 (exp MSB) is 0 -------
__device__ __forceinline__ unsigned pack15(unsigned short u) {
  return (u & 0x3FFFu) | ((u >> 1) & 0x4000u);
}
__device__ __forceinline__ unsigned short unpack15(unsigned v) {
  return (unsigned short)((v & 0x3FFFu) | ((v & 0x4000u) << 1));
}
__device__ __forceinline__ u64 unpack_word4(u64 a) {  // -> 4 fp16 in a u64
  u64 o = 0;
#pragma unroll
  for (int i = 0; i < 4; ++i)
    o |= (u64)unpack15((unsigned)(a >> (15*i)) & 0x7FFFu) << (16*i);
  return o;
}

__device__ __forceinline__ float dot8(half8 a, half8 b, float c) {
  typedef __attribute__((ext_vector_type(2))) _Float16 half2v;
  half2v a0 = {a[0],a[1]}, a1 = {a[2],a[3]}, a2 = {a[4],a[5]}, a3 = {a[6],a[7]};
  half2v b0 = {b[0],b[1]}, b1 = {b[2],b[3]}, b2 = {b[4],b[5]}, b3 = {b[6],b[7]};
  c = __builtin_amdgcn_fdot2(a0, b0, c, false);
  c = __builtin_amdgcn_fdot2(a1, b1, c, false);
  c = __builtin_amdgcn_fdot2(a2, b2, c, false);
  c = __builtin_amdgcn_fdot2(a3, b3, c, false);
  return c;
}

__device__ __forceinline__ float sigm(float x) { return 1.f/(1.f + __expf(-x)); }
__device__ __forceinline__ float tanh_f(float x) { return 2.f/(1.f + __expf(-2.f*x)) - 1.f; }

// ---------------- giE direct GEMM (r13/r14-proven) ---------------------------
__global__ __launch_bounds__(256) void giE_direct(
    const int* __restrict__ src, const float* __restrict__ emb,
    const float* __restrict__ Wih, const float* __restrict__ bih,
    float* __restrict__ gi)
{
  __shared__ _Float16 As[4096];
  __shared__ _Float16 Bs[4096];
  const int tid = threadIdx.x;
  const int lane = tid & 63;
  const int wv = tid >> 6;
  const int wr = wv >> 1, wc = wv & 1;
  const int mt = blockIdx.y, nt = blockIdx.x;
  floatx4 acc[4][4];
#pragma unroll
  for (int i=0;i<4;++i)
#pragma unroll
    for (int j=0;j<4;++j) acc[i][j] = (floatx4){0.f,0.f,0.f,0.f};
  const int r2 = tid >> 1, cb = (tid & 1) * 16;
  const int tok = src[mt*128 + r2];
  const float* arow = emb + (size_t)tok*EE;
  const float* brow = Wih + (size_t)(nt*128 + r2)*EE;
  const int g8 = (lane >> 4) * 8;
  const int lr = lane & 15;
  for (int kb = 0; kb < EE; kb += 32) {
    __syncthreads();
#pragma unroll
    for (int q = 0; q < 4; ++q) {
      const floatx4 va = *(const floatx4*)(arow + kb + cb + q*4);
      const floatx4 vb = *(const floatx4*)(brow + kb + cb + q*4);
#pragma unroll
      for (int e = 0; e < 4; ++e) {
        As[r2*32 + cb + q*4 + e] = (_Float16)va[e];
        Bs[r2*32 + cb + q*4 + e] = (_Float16)vb[e];
      }
    }
    __syncthreads();
    half8 af[4], bf[4];
#pragma unroll
    for (int i=0;i<4;++i) af[i] = *(const half8*)(As + (wr*64 + i*16 + lr)*32 + g8);
#pragma unroll
    for (int j=0;j<4;++j) bf[j] = *(const half8*)(Bs + (wc*64 + j*16 + lr)*32 + g8);
#pragma unroll
    for (int i=0;i<4;++i)
#pragma unroll
      for (int j=0;j<4;++j)
        acc[i][j] = __builtin_amdgcn_mfma_f32_16x16x32_f16(af[i], bf[j], acc[i][j], 0,0,0);
  }
  const int rm = 4*(lane>>4);
#pragma unroll
  for (int i=0;i<4;++i)
#pragma unroll
    for (int r=0;r<4;++r) {
      const int row = mt*128 + wr*64 + i*16 + rm + r;
#pragma unroll
      for (int j=0;j<4;++j) {
        const int col = nt*128 + wc*64 + j*16 + lr;
        gi[(size_t)row*1536 + col] = acc[i][j][r] + bih[col];
      }
    }
}

// ---------------- giD direct GEMM (r14-proven) --------------------------------
__global__ __launch_bounds__(256) void giD_direct(
    const int* __restrict__ tgt, const float* __restrict__ emb,
    const float* __restrict__ Wih, const float* __restrict__ bih,
    float* __restrict__ gi)
{
  __shared__ _Float16 As[4096];
  __shared__ _Float16 Bs[4096];
  const int tid = threadIdx.x;
  const int lane = tid & 63;
  const int wv = tid >> 6;
  const int wr = wv >> 1, wc = wv & 1;
  const int mt = blockIdx.y, nt = blockIdx.x;
  floatx4 acc[4][4];
#pragma unroll
  for (int i=0;i<4;++i)
#pragma unroll
    for (int j=0;j<4;++j) acc[i][j] = (floatx4){0.f,0.f,0.f,0.f};
  const int r2 = tid >> 1, cb = (tid & 1) * 16;
  const int R = mt*128 + r2;
  int tok = -1;
  if (R < 2528) { const int b_ = R/79, tt = R - b_*79; tok = tgt[b_*80 + tt]; }
  const float* arow = (tok >= 0) ? emb + (size_t)tok*EE : nullptr;
  const float* brow = Wih + (size_t)(nt*128 + r2)*EE;
  const int g8 = (lane >> 4) * 8;
  const int lr = lane & 15;
  for (int kb = 0; kb < EE; kb += 32) {
    __syncthreads();
    if (arow) {
#pragma unroll
      for (int q = 0; q < 4; ++q) {
        const floatx4 va = *(const floatx4*)(arow + kb + cb + q*4);
#pragma unroll
        for (int e = 0; e < 4; ++e) As[r2*32 + cb + q*4 + e] = (_Float16)va[e];
      }
    } else {
#pragma unroll
      for (int q = 0; q < 16; ++q) As[r2*32 + cb + q] = (_Float16)0.f;
    }
#pragma unroll
    for (int q = 0; q < 4; ++q) {
      const floatx4 vb = *(const floatx4*)(brow + kb + cb + q*4);
#pragma unroll
      for (int e = 0; e < 4; ++e) Bs[r2*32 + cb + q*4 + e] = (_Float16)vb[e];
    }
    __syncthreads();
    half8 af[4], bf[4];
#pragma unroll
    for (int i=0;i<4;++i) af[i] = *(const half8*)(As + (wr*64 + i*16 + lr)*32 + g8);
#pragma unroll
    for (int j=0;j<4;++j) bf[j] = *(const half8*)(Bs + (wc*64 + j*16 + lr)*32 + g8);
#pragma unroll
    for (int i=0;i<4;++i)
#pragma unroll
      for (int j=0;j<4;++j)
        acc[i][j] = __builtin_amdgcn_mfma_f32_16x16x32_f16(af[i], bf[j], acc[i][j], 0,0,0);
  }
  const int rm = 4*(lane>>4);
#pragma unroll
  for (int i=0;i<4;++i)
#pragma unroll
    for (int r=0;r<4;++r) {
      const int row = mt*128 + wv ? 0 : 0, dummy = 0; (void)dummy;
    }
  // (correct epilogue below)
#pragma unroll
  for (int i=0;i<4;++i)
#pragma unroll
    for (int r=0;r<4;++r) {
      const int row = mt*128 + wr*64 + i*16 + rm + r;
      if (row < 2528) {
#pragma unroll
        for (int j=0;j<4;++j) {
          const int col = nt*128 + wc*64 + j*16 + lr;
          gi[(size_t)row*1536 + col] = acc[i][j][r] + bih[col];
        }
      }
    }
}

// ---------------- outW fp32 -> fp16 (vectorized) -----------------------------
__global__ __launch_bounds__(256) void oWh_conv(
    const float* __restrict__ ow, _Float16* __restrict__ owh)
{
  const long total8 = (long)VV*1024/8;
  for (long i = (long)blockIdx.x*256 + threadIdx.x; i < total8; i += (long)gridDim.x*256) {
    const float* s_ = ow + i*8;
    const floatx4 a = *(const floatx4*)s_;
    const floatx4 b = *(const floatx4*)(s_ + 4);
    half8 h;
    h[0]=(_Float16)a[0]; h[1]=(_Float16)a[1]; h[2]=(_Float16)a[2]; h[3]=(_Float16)a[3];
    h[4]=(_Float16)b[0]; h[5]=(_Float16)b[1]; h[6]=(_Float16)b[2]; h[7]=(_Float16)b[3];
    *(half8*)(owh + i*8) = h;
  }
}

// ---------------- logits GEMM, XCD-clustered (r12-proven) --------------------
__global__ __launch_bounds__(256) void logits_gemm(
    const _Float16* __restrict__ A, const _Float16* __restrict__ Bm,
    const float* __restrict__ bias, float* __restrict__ out)
{
  const int p = blockIdx.x;
  const int x = p & 7, s = p >> 3;
  const int nt = x + 8*(s / 20);
  const int mt = s % 20;
  if (nt >= 250) return;
  __shared__ _Float16 As[4096];
  __shared__ _Float16 Bs[4096];
  const int tid = threadIdx.x;
  const int lane = tid & 63;
  const int wv = tid >> 6;
  const int wr = wv >> 1, wc = wv & 1;
  floatx4 acc[4][4];
#pragma unroll
  for (int i=0;i<4;++i)
#pragma unroll
    for (int j=0;j<4;++j) acc[i][j] = (floatx4){0.f,0.f,0.f,0.f};
  const int srow = lane >> 2;
  const int scol = (lane & 3) * 8;
  const _Float16* Ab = A + (size_t)(mt*128)*1024;
  const _Float16* Bb = Bm + (size_t)(nt*128)*1024;
  const int g8 = (lane >> 4) * 8;
  const int lr = lane & 15;
  for (int kb = 0; kb < 1024; kb += 32) {
    __syncthreads();
#pragma unroll
    for (int cc = 0; cc < 2; ++cc) {
      const int c = wv*2 + cc;
      gload16(Ab + (size_t)(c*16 + srow)*1024 + kb + scol, As + c*512);
      gload16(Bb + (size_t)(c*16 + srow)*1024 + kb + scol, Bs + c*512);
    }
    __syncthreads();
    half8 af[4], bf[4];
#pragma unroll
    for (int i=0;i<4;++i) af[i] = *(const half8*)(As + (wr*64 + i*16 + lr)*32 + g8);
#pragma unroll
    for (int j=0;j<4;++j) bf[j] = *(const half8*)(Bs + (wc*64 + j*16 + lr)*32 + g8);
#pragma unroll
    for (int i=0;i<4;++i)
#pragma unroll
      for (int j=0;j<4;++j)
        acc[i][j] = __builtin_amdgcn_mfma_f32_16x16x32_f16(af[i], bf[j], acc[i][j], 0,0,0);
  }
  const int rm = 4*(lane>>4);
#pragma unroll
  for (int i=0;i<4;++i)
#pragma unroll
    for (int r=0;r<4;++r) {
      const int row = mt*128 + wr*64 + i*16 + rm + r;
#pragma unroll
      for (int j=0;j<4;++j) {
        const int col = nt*128 + wc*64 + j*16 + lr;
        if (row < 2528) {
          const int b = row / 79;
          const int t = row - b*79;
          out[(size_t)(b*80 + t + 1)*VV + col] = acc[i][j][r] + bias[col];
        } else {
          out[(size_t)((row - 2528)*80)*VV + col] = 0.f;
        }
      }
    }
}

// ---------------- per-batch decoupled recurrence -----------------------------
// 256 WGs x 512 thr; blockIdx = q*32 + b (8 WGs per batch, q=0..7).
// WG (b,q) owns output cols [q*64, q*64+64); its Whh slice (3 gates x 64 cols
// x 512 k) lives in REGISTERS (48 VGPR/thread: thread = col jl=tid&63,
// k-chunk kq=tid>>6). No per-step weight traffic (fixes r3's L1-fill wall).
// Exchange: ONLY within the batch's 8 WGs (r9 tag-in-data, 15-bit pack +
// 4-bit tag; slot k&1 read / (k+1)&1 write; memset-0 = valid h(-1)+non-
// matching tags; WAR by the r9 register-dependence induction). No global
// coupling => each batch advances at its own rate (no 32-WG max-skew).
// Attention split across the batch's 8 WGs (redundant scores, 64-col ctx
// each), off the publish path via hatt snapshot.
#define SEQ_SMEM (80*512*2 + 512*2 + 512*2 + 3*64*8*4 + 2*80*4)
__global__ __launch_bounds__(512) void seq_pb(
    const float* __restrict__ eWhh, const float* __restrict__ dWhh,
    const float* __restrict__ ebhh, const float* __restrict__ dbhh,
    const float* __restrict__ giE, const float* __restrict__ giD,
    u64* __restrict__ hx,          // [2][32][128] u64, memset 0
    _Float16* __restrict__ comb)
{
  extern __shared__ char smem[];
  _Float16* eo_l = (_Float16*)smem;          // [80][512]
  _Float16* hbuf = eo_l + 80*512;            // [512]
  _Float16* hatt = hbuf + 512;               // [512]
  float* part = (float*)(hatt + 512);        // [3][64][8]
  float* sc = part + 3*64*8;                 // [80]
  float* aw = sc + 80;                       // [80]

  const int bi = blockIdx.x;
  const int q = bi >> 5, b = bi & 31;
  const int tid = threadIdx.x;
  const int lane = tid & 63;
  const int wv = tid >> 6;
  const int jl = tid & 63;        // local col
  const int kq = tid >> 6;        // k-chunk 0..7
  const int j  = q*64 + jl;       // global col

  half8 wreg[3][8];               // 48 VGPRs of weights
  auto loadW = [&](const float* W){
#pragma unroll
    for (int g = 0; g < 3; ++g)
#pragma unroll
      for (int c = 0; c < 8; ++c) {
        const float* s8 = W + ((size_t)(g*512 + j))*512 + kq*64 + c*8;
        const floatx4 a = *(const floatx4*)s8;
        const floatx4 d = *(const floatx4*)(s8 + 4);
        half8 h;
        h[0]=(_Float16)a[0]; h[1]=(_Float16)a[1]; h[2]=(_Float16)a[2]; h[3]=(_Float16)a[3];
        h[4]=(_Float16)d[0]; h[5]=(_Float16)d[1]; h[6]=(_Float16)d[2]; h[7]=(_Float16)d[3];
        wreg[g][c] = h;
      }
  };

  auto consume = [&](int slotR, u64 rtag){
    if (tid < 112) {               // 112 partner words; own 16 words stay local
      const int m = tid + (tid >= q*16 ? 16 : 0);
      const u64* sp = hx + (size_t)slotR*4096 + b*128 + m;
      u64 v = aload(sp);
      int guard = 0;
      while ((v >> 60) != rtag && guard < (1<<22)) { v = aload(sp); ++guard; }
      *(u64*)&hbuf[m*4] = unpack_word4(v);
    }
    __syncthreads();
  };
  auto publish = [&](int slotW, u64 wtag){
    if (tid < 16) {
      const int m = q*16 + tid;
      u64 wq = wtag << 60;
#pragma unroll
      for (int e = 0; e < 4; ++e) {
        union { _Float16 h; unsigned short u; } cv; cv.h = hbuf[m*4 + e];
        wq |= (u64)pack15(cv.u) << (15*e);
      }
      astore(hx + (size_t)slotW*4096 + b*128 + m, wq);
    }
  };

  float hp = 0.f;                 // fp32 h_prev for col j (tid<64 only)
  auto gru = [&](float gr_, float gz_, float gn_, float bR, float bZ, float bN){
    half8 hv[8];
#pragma unroll
    for (int c = 0; c < 8; ++c) hv[c] = *(const half8*)&hbuf[kq*64 + c*8];
    float p0 = 0.f, p1 = 0.f, p2 = 0.f;
#pragma unroll
    for (int c = 0; c < 8; ++c) {
      p0 = dot8(wreg[0][c], hv[c], p0);
      p1 = dot8(wreg[1][c], hv[c], p1);
      p2 = dot8(wreg[2][c], hv[c], p2);
    }
    part[(0*64 + jl)*8 + kq] = p0;
    part[(1*64 + jl)*8 + kq] = p1;
    part[(2*64 + jl)*8 + kq] = p2;
    __syncthreads();
    if (tid < 64) {
      float a0 = 0.f, a1 = 0.f, a2 = 0.f;
#pragma unroll
      for (int e = 0; e < 8; ++e) {
        a0 += part[(0*64 + tid)*8 + e];
        a1 += part[(1*64 + tid)*8 + e];
        a2 += part[(2*64 + tid)*8 + e];
      }
      const float rg = sigm(gr_ + a0 + bR);
      const float zg = sigm(gz_ + a1 + bZ);
      const float ng = tanh_f(gn_ + rg*(a2 + bN));
      const float hn = (1.f - zg)*ng + zg*hp;     // |hn| <= 1 by induction
      hp = hn;
      hbuf[q*64 + tid] = (_Float16)hn;
    }
    __syncthreads();
  };

  auto attention = [&](int trow){
    const half8 hf = *(const half8*)&hatt[lane*8];
#pragma unroll 2
    for (int i = 0; i < 10; ++i) {               // 8 waves x 10 scores
      const int s = wv*10 + i;
      const half8 ev = *(const half8*)&eo_l[s*512 + lane*8];
      float pt = dot8(ev, hf, 0.f);
#pragma unroll
      for (int o = 32; o; o >>= 1) pt += __shfl_xor(pt, o);
      if (lane == 0) sc[s] = pt;
    }
    __syncthreads();
    if (wv == 0) {                               // softmax over 80 (wave 0)
      const float v0 = sc[lane];
      const float v1 = (lane < 16) ? sc[64+lane] : -1e30f;
      float m = fmaxf(v0, v1);
#pragma unroll
      for (int o = 32; o; o >>= 1) m = fmaxf(m, __shfl_xor(m, o));
      const float e0 = __expf(v0 - m);
      const float e1 = (lane < 16) ? __expf(v1 - m) : 0.f;
      float ssum = e0 + e1;
#pragma unroll
      for (int o = 32; o; o >>= 1) ssum += __shfl_xor(ssum, o);
      const float inv = 1.f/ssum;
      aw[lane] = e0*inv;
      if (lane < 16) aw[64+lane] = e1*inv;
    }
    __syncthreads();
    if (tid < 64) {                              // own 64 ctx cols
      float c = 0.f;
#pragma unroll 8
      for (int s = 0; s < SS; ++s) c += aw[s] * (float)eo_l[s*512 + q*64 + tid];
      _Float16* cr = comb + ((size_t)b*79 + trow)*1024;
      cr[q*64 + tid]       = hatt[q*64 + tid];
      cr[512 + q*64 + tid] = (_Float16)c;
    }
    __syncthreads();
  };

  // init: own quarter of h(-1) = 0 in LDS (global slots pre-memset 0)
  if (tid < 128) *(u64*)&hbuf[tid*4] = 0ull;
  loadW(eWhh);
  float ebR=0.f, ebZ=0.f, ebN=0.f, dbR=0.f, dbZ=0.f, dbN=0.f;
  if (tid < 64) {
    ebR = ebhh[j]; ebZ = ebhh[512+j]; ebN = ebhh[1024+j];
    dbR = dbhh[j]; dbZ = dbhh[512+j]; dbN = dbhh[1024+j];
  }
  __syncthreads();

  // -------- encoder: k = 0..79 --------
  for (int k = 0; k < SS; ++k) {
    float gr_=0.f, gz_=0.f, gn_=0.f;
    if (tid < 64) {
      const float* gi = giE + ((size_t)b*SS + k)*1536;
      gr_ = gi[j]; gz_ = gi[512+j]; gn_ = gi[1024+j];   // prefetch pre-poll
    }
    consume(k & 1, (u64)(k & 15));
    if (k > 0 && tid < 128)                              // stash h(k-1)
      *(u64*)&eo_l[(k-1)*512 + tid*4] = *(const u64*)&hbuf[tid*4];
    gru(gr_, gz_, gn_, ebR, ebZ, ebN);
    publish((k+1) & 1, (u64)((k+1) & 15));
  }

  loadW(dWhh);   // per-thread regs, no sync needed

  // -------- decoder: k = 80..158 (t = k-80) --------
  for (int t = 0; t < TT-1; ++t) {
    const int k = 80 + t;
    float gr_=0.f, gz_=0.f, gn_=0.f;
    if (tid < 64) {
      const float* gi = giD + ((size_t)b*79 + t)*1536;
      gr_ = gi[j]; gz_ = gi[512+j]; gn_ = gi[1024+j];
    }
    consume(k & 1, (u64)(k & 15));
    if (tid < 128) {
      if (t == 0) *(u64*)&eo_l[79*512 + tid*4] = *(const u64*)&hbuf[tid*4];
      else        *(u64*)&hatt[tid*4]          = *(const u64*)&hbuf[tid*4];
    }
    gru(gr_, gz_, gn_, dbR, dbZ, dbN);
    publish((k+1) & 1, (u64)((k+1) & 15));
    if (t > 0) attention(t-1);                           // off the publish path
  }

  // final: h(158) in slot 1, tag 15 (own quarter already in hbuf)
  if (tid < 112) {
    const int m = tid + (tid >= q*16 ? 16 : 0);
    const u64* sp = hx + (size_t)4096 + b*128 + m;
    u64 v = aload(sp);
    int guard = 0;
    while ((v >> 60) != 15ull && guard < (1<<22)) { v = aload(sp); ++guard; }
    *(u64*)&hbuf[m*4] = unpack_word4(v);
  }
  __syncthreads();
  if (tid < 128) *(u64*)&hatt[tid*4] = *(const u64*)&hbuf[tid*4];
  __syncthreads();
  attention(TT-2);
}

extern "C" void kernel_launch(void* const* d_in, const int* in_sizes, int n_in,
                              void* d_out, int out_size, void* d_ws, size_t ws_size,
                              hipStream_t stream) {
  (void)in_sizes; (void)n_in; (void)out_size; (void)ws_size;
  const int*   src  = (const int*)d_in[0];
  const int*   tgt  = (const int*)d_in[1];
  const float* emb  = (const float*)d_in[2];
  const float* eWih = (const float*)d_in[3];
  const float* eWhh = (const float*)d_in[4];
  const float* ebih = (const float*)d_in[5];
  const float* ebhh = (const float*)d_in[6];
  const float* dWih = (const float*)d_in[7];
  const float* dWhh = (const float*)d_in[8];
  const float* dbih = (const float*)d_in[9];
  const float* dbhh = (const float*)d_in[10];
  const float* outW = (const float*)d_in[11];
  const float* outb = (const float*)d_in[12];
  float* out = (float*)d_out;

  char* p = (char*)d_ws;
  auto alloc = [&](size_t n){ char* r = p; p += (n + 255) & ~(size_t)255; return r; };
  _Float16* oWh  = (_Float16*)alloc((size_t)VV*1024*2);
  float*    giE  = (float*)alloc((size_t)2560*1536*4);
  float*    giD  = (float*)alloc((size_t)2560*1536*4);
  u64*      hx   = (u64*)alloc((size_t)2*32*128*8);
  _Float16* comb = (_Float16*)alloc((size_t)2560*1024*2);

  hipMemsetAsync(hx, 0, (size_t)2*32*128*8, stream);   // slots+tags = 0
  giE_direct<<<dim3(12,20), 256, 0, stream>>>(src, emb, eWih, ebih, giE);
  giD_direct<<<dim3(12,20), 256, 0, stream>>>(tgt, emb, dWih, dbih, giD);
  oWh_conv<<<1024, 256, 0, stream>>>(outW, oWh);
  hipFuncSetAttribute((const void*)seq_pb,
                      hipFuncAttributeMaxDynamicSharedMemorySize, SEQ_SMEM);
  seq_pb<<<256, 512, SEQ_SMEM, stream>>>(eWhh, dWhh, ebhh, dbhh, giE, giD,
                                         hx, comb);
  logits_gemm<<<5120, 256, 0, stream>>>(comb, oWh, outb, out);
}